// Round 22
// baseline (842.742 us; speedup 1.0000x reference)
//
#include <hip/hip_runtime.h>
#include <math.h>

#define B_ 8
#define L_ 256
#define N_ 22
#define C_ 128
#define H_ 8
#define DK_ 16
#define DFF_ 512
#define NL_ 6
#define MTOK (B_*L_*N_)   // 45056

typedef __bf16 bf16x8 __attribute__((ext_vector_type(8)));
typedef float  f32x4  __attribute__((ext_vector_type(4)));

__device__ __forceinline__ float wave_sum(float v){
#pragma unroll
  for (int i = 32; i >= 1; i >>= 1) v += __shfl_xor(v, i, 64);
  return v;
}

// fast mish: x * tanh(softplus(x)) == x*num/(num+2), num=t(t+2), t=e^x.
// den = num+2 >= 2 -> v_rcp_f32 (~1ulp) safe; error far below bf16 rounding.
__device__ __forceinline__ float mishf(float x){
  float t = __expf(fminf(x, 20.0f));
  float num = t * (t + 2.0f);
  return x * num * __builtin_amdgcn_rcpf(num + 2.0f);
}

// ---------------- fused entry: o = x + LN(x+pe; peg,peb); y = LN(o; g1,b1) ------
__global__ __launch_bounds__(256) void pe_ln_kernel(
    const float* __restrict__ x, const float* __restrict__ g,
    const float* __restrict__ b, const float* __restrict__ g1,
    const float* __restrict__ b1, float* __restrict__ yf,
    __bf16* __restrict__ yb)
{
  int row  = (blockIdx.x * 256 + threadIdx.x) >> 6;   // token index
  int lane = threadIdx.x & 63;
  if (row >= MTOK) return;
  int bl = row / N_;            // b*L + l
  int l  = bl & (L_ - 1);
  const float* xr = x + (size_t)row * C_;
  float x0 = xr[lane], x1 = xr[lane + 64];
  int c0 = lane, c1 = lane + 64;
  const float LOG1E4 = 9.210340371976184f;
  float e0 = __expf(LOG1E4 * (-2.0f * (float)c0 / 128.0f));
  float e1 = __expf(LOG1E4 * (-2.0f * (float)c1 / 128.0f));
  float a0 = (float)l * e0, a1 = (float)l * e1;
  float pe0 = (c0 & 1) ? cosf(a0) : sinf(a0);
  float pe1 = (c1 & 1) ? cosf(a1) : sinf(a1);
  float t0 = x0 + pe0, t1 = x1 + pe1;
  float mean = wave_sum(t0 + t1) * (1.0f/128.0f);
  float d0 = t0 - mean, d1 = t1 - mean;
  float var = wave_sum(d0*d0 + d1*d1) * (1.0f/128.0f);
  float inv = rsqrtf(var + 1e-5f);
  float o0 = x0 + d0 * inv * g[c0] + b[c0];
  float o1 = x1 + d1 * inv * g[c1] + b[c1];
  float m2 = wave_sum(o0 + o1) * (1.0f/128.0f);
  float e0d = o0 - m2, e1d = o1 - m2;
  float v2 = wave_sum(e0d*e0d + e1d*e1d) * (1.0f/128.0f);
  float i2 = rsqrtf(v2 + 1e-5f);
  float y0 = e0d * i2 * g1[c0] + b1[c0];
  float y1 = e1d * i2 * g1[c1] + b1[c1];
  float* yrow = yf + (size_t)row * C_;
  yrow[c0] = y0;
  yrow[c1] = y1;
  __bf16* brow = yb + (size_t)row * C_;
  brow[c0] = (__bf16)y0;
  brow[c1] = (__bf16)y1;
}

// ---------------- weight pack fp32 -> bf16 arena, FRAGMENT-MAJOR ----------------
// frag (nb,kb): rows nb*16..+15 x k kb*32..+31 as 512 contiguous elems:
// element (n = nb*16 + (lane&15), k = kb*32 + (lane>>4)*8 + j) at
// off = ((nb*KB + kb)*64 + lane)*8 + j  -> 1KB coalesced wave burst per frag.
// QKV [0,589824) per-layer 49152 (nb<24,KB=4); Wo [..688128) (nb<8,KB=4);
// W1 [..1081344) (nb<32,KB=4); W2 [..1474560) (nb<8,KB=16) with the FF1->FF2
// k-permutation composed in: src k-within-32 = (j<4 ? lh*4+j : 16+lh*4+(j-4)).
#define WQKV_END 589824
#define WO_END   688128
#define W1_END   1081344
#define WTOT     1474560
__global__ __launch_bounds__(256) void wpack_kernel(
    const float* __restrict__ Wq, const float* __restrict__ Wk,
    const float* __restrict__ Wv, const float* __restrict__ Wo,
    const float* __restrict__ W1, const float* __restrict__ W2,
    __bf16* __restrict__ dst)
{
  int i = blockIdx.x * 256 + threadIdx.x;
  float v;
  if (i < WQKV_END) {
    int li = i / 49152, rem = i % 49152;
    int j = rem & 7, lane = (rem >> 3) & 63, fr = rem >> 9;
    int kb = fr & 3, nb = fr >> 2;
    int n = nb*16 + (lane & 15);
    int k = kb*32 + (lane >> 4)*8 + j;
    int which = n >> 7, nr = n & 127;
    const float* W = which == 0 ? Wq : which == 1 ? Wk : Wv;
    v = W[li*16384 + nr*128 + k];
  } else if (i < WO_END) {
    int rel = i - WQKV_END;
    int li = rel / 16384, rem = rel % 16384;
    int j = rem & 7, lane = (rem >> 3) & 63, fr = rem >> 9;
    int kb = fr & 3, nb = fr >> 2;
    int n = nb*16 + (lane & 15), k = kb*32 + (lane >> 4)*8 + j;
    v = Wo[li*16384 + n*128 + k];
  } else if (i < W1_END) {
    int rel = i - WO_END;
    int li = rel / 65536, rem = rel % 65536;
    int j = rem & 7, lane = (rem >> 3) & 63, fr = rem >> 9;
    int kb = fr & 3, nb = fr >> 2;
    int n = nb*16 + (lane & 15), k = kb*32 + (lane >> 4)*8 + j;
    v = W1[li*65536 + n*128 + k];
  } else {
    int rel = i - W1_END;
    int li = rel / 65536, rem = rel % 65536;
    int j = rem & 7, lane = (rem >> 3) & 63, fr = rem >> 9;
    int kb = fr & 15, nb = fr >> 4;
    int n = nb*16 + (lane & 15);
    int lh = lane >> 4;
    int base = kb*32;
    int srck = base + (j < 4 ? lh*4 + j : 16 + lh*4 + (j - 4));
    v = W2[li*65536 + n*512 + srck];
  }
  dst[i] = (__bf16)v;
}

// pack QKV biases: [NL][384] fp32
__global__ __launch_bounds__(256) void bpack_kernel(
    const float* __restrict__ bq, const float* __restrict__ bk,
    const float* __restrict__ bv, float* __restrict__ dst)
{
  int i = blockIdx.x * 256 + threadIdx.x;   // < NL*384
  int li = i / 384, p = i % 384;
  float v = p < 128 ? bq[li*128 + p] : p < 256 ? bk[li*128 + p - 128] : bv[li*128 + p - 256];
  dst[i] = v;
}

// ---------------- LDS-staged gemm: B-panel (32KB, contiguous frags) in LDS ------
// Block = 64 tokens, 4 waves; panel = frags [blockIdx.y*32, +32) staged linearly.
// LN=0: outb = bf16(acc+bias). LN=1 (Ntot==128): v=acc+bias+res; y=LN(v)->outf+outb.
template<int LN>
__global__ __launch_bounds__(256, 4) void sgemm_kernel(
    const __bf16* __restrict__ A, const __bf16* __restrict__ Bw,
    const float* __restrict__ bias, const float* __restrict__ res,
    __bf16* __restrict__ outb, float* __restrict__ outf,
    const float* __restrict__ g1, const float* __restrict__ b1v,
    int Ntot)
{
  __shared__ __align__(16) char sW[32768];
  const int tid  = threadIdx.x;
  const int lane = tid & 63;
  const int wv   = tid >> 6;
  const int l15  = lane & 15;
  const int lh   = lane >> 4;
  const int tok0 = (blockIdx.x * 4 + wv) * 16;
  const int bn   = blockIdx.y * 128;

  // stage panel: contiguous 32KB at arena byte offset blockIdx.y*32768
  const char* wsrc = (const char*)Bw + (size_t)blockIdx.y * 32768;
#pragma unroll
  for (int i = 0; i < 8; ++i) {
    int id = i*256 + tid;
    __builtin_amdgcn_global_load_lds((const unsigned int*)(wsrc + (size_t)id*16),
        (unsigned int*)(sW + (size_t)(i*256 + wv*64)*16), 16, 0, 0);
  }

  bf16x8 az[4];
#pragma unroll
  for (int ks = 0; ks < 4; ++ks)
    az[ks] = *(const bf16x8*)(A + (size_t)(tok0 + l15) * 128 + ks*32 + lh*8);

  __syncthreads();   // staging visible (compiler drains vmcnt before barrier)

  f32x4 acc[8] = {};
#pragma unroll
  for (int ks = 0; ks < 4; ++ks)
#pragma unroll
    for (int fc = 0; fc < 8; ++fc) {
      bf16x8 bw = *(const bf16x8*)(sW + (size_t)(fc*4 + ks)*1024 + lane*16);
      acc[fc] = __builtin_amdgcn_mfma_f32_16x16x32_bf16(az[ks], bw, acc[fc], 0, 0, 0);
    }

  if (LN == 0) {
#pragma unroll
    for (int fc = 0; fc < 8; ++fc) {
      int col = bn + fc*16 + l15;
      float bc = bias[col];
#pragma unroll
      for (int r = 0; r < 4; ++r)
        outb[(size_t)(tok0 + lh*4 + r) * Ntot + col] = (__bf16)(acc[fc][r] + bc);
    }
  } else {
#pragma unroll
    for (int fc = 0; fc < 8; ++fc) {
      int col = fc*16 + l15;
      float bc = bias[col];
#pragma unroll
      for (int r = 0; r < 4; ++r)
        acc[fc][r] += bc + res[(size_t)(tok0 + lh*4 + r) * 128 + col];
    }
    float mean[4], inv[4];
#pragma unroll
    for (int r = 0; r < 4; ++r) {
      float s = 0.0f, q = 0.0f;
#pragma unroll
      for (int fc = 0; fc < 8; ++fc) { s += acc[fc][r]; q += acc[fc][r]*acc[fc][r]; }
#pragma unroll
      for (int msk = 1; msk <= 8; msk <<= 1) {
        s += __shfl_xor(s, msk, 64);
        q += __shfl_xor(q, msk, 64);
      }
      float m = s * (1.0f/128.0f);
      mean[r] = m;
      inv[r]  = rsqrtf(q * (1.0f/128.0f) - m*m + 1e-5f);
    }
#pragma unroll
    for (int fc = 0; fc < 8; ++fc) {
      int col = fc*16 + l15;
      float gc = g1[col], bc = b1v[col];
#pragma unroll
      for (int r = 0; r < 4; ++r) {
        float y = (acc[fc][r] - mean[r]) * inv[r] * gc + bc;
        size_t idx = (size_t)(tok0 + lh*4 + r) * 128 + col;
        outf[idx] = y;
        outb[idx] = (__bf16)y;
      }
    }
  }
}

// ---------------- fused FF residual block v10: pipelined 16KB-chunk dbuf --------
// Block = 64 tokens, 4 waves (wave = 16 tokens, ALL 128 output cols).
// 16 chunks of 32 dff; double-buffered in 2x16KB (32KB). Issue next chunk's
// global_load_lds before computing current. LN epilogue wave-local.
template<int SECOND>
__global__ __launch_bounds__(256, 4) void ffuse_kernel(
    const __bf16* __restrict__ zb, const float* __restrict__ resf,
    const __bf16* __restrict__ W1g, const __bf16* __restrict__ W2g,
    const float* __restrict__ b1, const float* __restrict__ b2,
    const float* __restrict__ g1, const float* __restrict__ b1v,
    const float* __restrict__ g2, const float* __restrict__ b2v,
    __bf16* __restrict__ outb, float* __restrict__ outf,
    float* __restrict__ hout)
{
  __shared__ __align__(16) char smem[32768];   // 2 x (8KB sW1 + 8KB sW2)

  const int tid  = threadIdx.x;
  const int lane = tid & 63;
  const int wv   = tid >> 6;
  const int l15  = lane & 15;
  const int lh   = lane >> 4;
  const int tok0 = blockIdx.x * 64 + wv * 16;

  // z B-frags (token tok0+l15, k = ks*32 + lh*8) -- proven global path
  bf16x8 bz[4];
#pragma unroll
  for (int ks = 0; ks < 4; ++ks)
    bz[ks] = *(const bf16x8*)(zb + (size_t)(tok0 + l15) * 128 + ks*32 + lh*8);

  f32x4 accC[8] = {};

  // STAGE(chunk c -> buffer bb): W1c 8KB contiguous; W2c 8 frags (kb == c).
#define STAGE_W(c, bb) do { \
    char* sW1d = smem + (bb)*16384; \
    char* sW2d = sW1d + 8192; \
    _Pragma("unroll") \
    for (int i = 0; i < 2; ++i) { \
      int id = i*256 + tid; \
      const char* gsrc = (const char*)W1g + (size_t)(c)*8192 + (size_t)id*16; \
      __builtin_amdgcn_global_load_lds((const unsigned int*)gsrc, \
          (unsigned int*)(sW1d + (size_t)(i*256 + wv*64)*16), 16, 0, 0); \
    } \
    _Pragma("unroll") \
    for (int i = 0; i < 2; ++i) { \
      int f = i*4 + wv; \
      const char* gsrc = (const char*)W2g + ((size_t)(f*16 + (c))*64 + lane)*16; \
      __builtin_amdgcn_global_load_lds((const unsigned int*)gsrc, \
          (unsigned int*)(sW2d + (size_t)f * 1024), 16, 0, 0); \
    } \
  } while (0)

  STAGE_W(0, 0);
  __syncthreads();                 // chunk 0 staged

  int cur = 0;
  for (int ch = 0; ch < 16; ++ch) {
    if (ch < 15) STAGE_W(ch + 1, cur ^ 1);   // issue next chunk's loads first

    const char* sW1 = smem + cur*16384;
    const char* sW2 = sW1 + 8192;

    // ---- FF1 (swapped): accM[fn] over this 32-dff chunk ----
    f32x4 accM[2] = {};
#pragma unroll
    for (int ks = 0; ks < 4; ++ks)
#pragma unroll
      for (int fn = 0; fn < 2; ++fn) {
        bf16x8 aw = *(const bf16x8*)(sW1 + (size_t)(fn*4 + ks)*1024 + lane*16);
        accM[fn] = __builtin_amdgcn_mfma_f32_16x16x32_bf16(aw, bz[ks], accM[fn], 0, 0, 0);
      }
    // bias + mish
#pragma unroll
    for (int fn = 0; fn < 2; ++fn) {
      f32x4 bb = *(const f32x4*)(b1 + ch*32 + fn*16 + lh*4);
#pragma unroll
      for (int r = 0; r < 4; ++r)
        accM[fn][r] = mishf(accM[fn][r] + bb[r]);
    }
    // ---- FF2: one A-frag from accM pair (W2 k-permutation composed at pack) ----
    {
      bf16x8 am;
#pragma unroll
      for (int j = 0; j < 4; ++j) {
        am[j]     = (__bf16)accM[0][j];
        am[j + 4] = (__bf16)accM[1][j];
      }
#pragma unroll
      for (int fc = 0; fc < 8; ++fc) {
        bf16x8 bw = *(const bf16x8*)(sW2 + (size_t)fc*1024 + lane*16);
        accC[fc] = __builtin_amdgcn_mfma_f32_16x16x32_bf16(am, bw, accC[fc], 0, 0, 0);
      }
    }
    __syncthreads();   // prefetch drained (after compute) + buffer-reuse fence
    cur ^= 1;
  }
#undef STAGE_W

  // ---- epilogue: bias + residual, wave-local LN (proven sgemm<1> shape) ----
#pragma unroll
  for (int fc = 0; fc < 8; ++fc) {
    int col = fc*16 + l15;
    float bc = b2[col];
#pragma unroll
    for (int r = 0; r < 4; ++r)
      accC[fc][r] += bc + resf[(size_t)(tok0 + lh*4 + r) * 128 + col];
  }
  float mean[4], inv[4];
#pragma unroll
  for (int r = 0; r < 4; ++r) {
    float s = 0.0f, q = 0.0f;
#pragma unroll
    for (int fc = 0; fc < 8; ++fc) { s += accC[fc][r]; q += accC[fc][r]*accC[fc][r]; }
#pragma unroll
    for (int msk = 1; msk <= 8; msk <<= 1) {
      s += __shfl_xor(s, msk, 64);
      q += __shfl_xor(q, msk, 64);
    }
    float m = s * (1.0f/128.0f);
    mean[r] = m;
    inv[r]  = rsqrtf(q * (1.0f/128.0f) - m*m + 1e-5f);
  }

  if (SECOND == 0) {
#pragma unroll
    for (int fc = 0; fc < 8; ++fc) {
      int col = fc*16 + l15;
      float gc = g1[col], bc = b1v[col];
#pragma unroll
      for (int r = 0; r < 4; ++r) {
        float y = (accC[fc][r] - mean[r]) * inv[r] * gc + bc;
        size_t idx = (size_t)(tok0 + lh*4 + r) * 128 + col;
        outf[idx] = y;
        outb[idx] = (__bf16)y;
      }
    }
  } else {
    // h = LN_F(v)
#pragma unroll
    for (int fc = 0; fc < 8; ++fc) {
      int col = fc*16 + l15;
      float gc = g1[col], bc = b1v[col];
#pragma unroll
      for (int r = 0; r < 4; ++r) {
        float h = (accC[fc][r] - mean[r]) * inv[r] * gc + bc;
        accC[fc][r] = h;
        if (hout) hout[(size_t)(tok0 + lh*4 + r) * 128 + col] = h;
      }
    }
    if (g2 != nullptr) {
#pragma unroll
      for (int r = 0; r < 4; ++r) {
        float s = 0.0f, q = 0.0f;
#pragma unroll
        for (int fc = 0; fc < 8; ++fc) { s += accC[fc][r]; q += accC[fc][r]*accC[fc][r]; }
#pragma unroll
        for (int msk = 1; msk <= 8; msk <<= 1) {
          s += __shfl_xor(s, msk, 64);
          q += __shfl_xor(q, msk, 64);
        }
        float m = s * (1.0f/128.0f);
        mean[r] = m;
        inv[r]  = rsqrtf(q * (1.0f/128.0f) - m*m + 1e-5f);
      }
#pragma unroll
      for (int fc = 0; fc < 8; ++fc) {
        int col = fc*16 + l15;
        float gc = g2[col], bc = b2v[col];
#pragma unroll
        for (int r = 0; r < 4; ++r) {
          float y = (accC[fc][r] - mean[r]) * inv[r] * gc + bc;
          size_t idx = (size_t)(tok0 + lh*4 + r) * 128 + col;
          outf[idx] = y;
          outb[idx] = (__bf16)y;
        }
      }
    }
  }
}

// ---------------- attention over nodes, block per (b,l), scatter-scrambled out ---
// K/V staged in LDS as BF16 via vectorized 16B copies (11KB, no convert VALU);
// conversion to fp32 at read time -- numerically identical (source is bf16).
__global__ __launch_bounds__(256) void attn_kernel(
    const __bf16* __restrict__ qkv, __bf16* __restrict__ out)
{
  __shared__ __bf16 Ks[N_ * C_];
  __shared__ __bf16 Vs[N_ * C_];
  int bl = blockIdx.x;            // b*L + l
  int b  = bl >> 8;
  int l  = bl & (L_ - 1);
  size_t mb = (size_t)bl * N_;
  // vectorized staging: per row of 128 bf16 = 16 chunks of 16B
  // total chunks = 22*16 = 352 per matrix; 256 threads -> 2 iters (padded)
  for (int id = threadIdx.x; id < N_ * 16; id += 256) {
    int row = id >> 4, c16 = id & 15;
    const uint4* ksrc = (const uint4*)(qkv + (mb + row) * 384 + 128) + c16;
    const uint4* vsrc = (const uint4*)(qkv + (mb + row) * 384 + 256) + c16;
    *((uint4*)(Ks + row * C_) + c16) = *ksrc;
    *((uint4*)(Vs + row * C_) + c16) = *vsrc;
  }
  __syncthreads();
  int h  = threadIdx.x >> 5;
  int nq = threadIdx.x & 31;
  if (nq >= N_) return;
  float qr[DK_];
  const __bf16* qp = qkv + (mb + nq) * 384 + h * DK_;
#pragma unroll
  for (int d = 0; d < DK_; ++d) qr[d] = (float)qp[d];
  float sc[N_];
#pragma unroll
  for (int m = 0; m < N_; ++m) {
    float s = 0.0f;
#pragma unroll
    for (int d = 0; d < DK_; ++d) s = fmaf(qr[d], (float)Ks[m*C_ + h*DK_ + d], s);
    sc[m] = s * 0.25f;
  }
  float mx = -1e30f;
#pragma unroll
  for (int m = 0; m < N_; ++m) mx = fmaxf(mx, sc[m]);
  float sum = 0.0f;
#pragma unroll
  for (int m = 0; m < N_; ++m) { sc[m] = __expf(sc[m] - mx); sum += sc[m]; }
  float rs = __builtin_amdgcn_rcpf(sum);
  float o[DK_];
#pragma unroll
  for (int d = 0; d < DK_; ++d) o[d] = 0.0f;
#pragma unroll
  for (int m = 0; m < N_; ++m)
#pragma unroll
    for (int d = 0; d < DK_; ++d) o[d] = fmaf(sc[m], (float)Vs[m*C_ + h*DK_ + d], o[d]);
  int flat = nq * L_ + l;
  int l2 = flat / N_;
  int n2 = flat - l2 * N_;
  __bf16* op = out + ((size_t)((b * L_ + l2) * N_ + n2)) * C_ + h * DK_;
#pragma unroll
  for (int d = 0; d < DK_; ++d) op[d] = (__bf16)(o[d] * rs);
}

extern "C" void kernel_launch(void* const* d_in, const int* in_sizes, int n_in,
                              void* d_out, int out_size, void* d_ws, size_t ws_size,
                              hipStream_t stream) {
  const float* x    = (const float*)d_in[0];
  const float* Wq   = (const float*)d_in[1];
  const float* bq   = (const float*)d_in[2];
  const float* Wk   = (const float*)d_in[3];
  const float* bk   = (const float*)d_in[4];
  const float* Wv   = (const float*)d_in[5];
  const float* bv   = (const float*)d_in[6];
  const float* Wo   = (const float*)d_in[7];
  const float* bo   = (const float*)d_in[8];
  const float* W1   = (const float*)d_in[9];
  const float* bf1  = (const float*)d_in[10];
  const float* W2   = (const float*)d_in[11];
  const float* bf2  = (const float*)d_in[12];
  const float* ln1g = (const float*)d_in[13];
  const float* ln1b = (const float*)d_in[14];
  const float* lnAg = (const float*)d_in[15];
  const float* lnAb = (const float*)d_in[16];
  const float* lnFg = (const float*)d_in[17];
  const float* lnFb = (const float*)d_in[18];
  const float* peg  = (const float*)d_in[19];
  const float* peb  = (const float*)d_in[20];

  float* out = (float*)d_out;
  char*  ws  = (char*)d_ws;
  const size_t U = (size_t)MTOK * C_;

  __bf16* wbf   = (__bf16*)ws;                         // 2,949,120 B weight arena
  float*  bqkv  = (float*)(ws + 2949120);              // NL*384*4
  float*  yf    = (float*)(ws + 2958592);              // U*4 fp32 residual/LN base
  __bf16* yb    = (__bf16*)(ws + 2958592 + U*4);       // U*2 bf16 LN out
  __bf16* qkvb  = (__bf16*)(ws + 2958592 + U*6);       // 3U*2 packed QKV
  __bf16* sb    = (__bf16*)(ws + 2958592 + U*12);      // U*2 scrambled attn out

  dim3 blk(256);
  const int lnGrid = MTOK / 4;
  dim3 gqkv(MTOK/64, 3);
  dim3 g64(MTOK/64, 1);

  wpack_kernel<<<WTOT/256, blk, 0, stream>>>(Wq, Wk, Wv, Wo, W1, W2, wbf);
  bpack_kernel<<<NL_*384/256, blk, 0, stream>>>(bq, bk, bv, bqkv);
  pe_ln_kernel<<<lnGrid, blk, 0, stream>>>(x, peg, peb, ln1g, ln1b, yf, yb);

  for (int li = 0; li < NL_; ++li) {
    const __bf16* wqkv_b = wbf + (size_t)li * 49152;
    const __bf16* wo_b   = wbf + WQKV_END + (size_t)li * 16384;
    const __bf16* w1_b   = wbf + WO_END   + (size_t)li * 65536;
    const __bf16* w2_b   = wbf + W1_END   + (size_t)li * 65536;
    const float* bqkv_l = bqkv + (size_t)li * 384;
    const float* bo_l = bo + (size_t)li * 128;
    const float* b1_l = bf1 + (size_t)li * 512;
    const float* b2_l = bf2 + (size_t)li * 128;
    const float* gA = lnAg + (size_t)li * C_; const float* bA = lnAb + (size_t)li * C_;
    const float* gF = lnFg + (size_t)li * C_; const float* bF = lnFb + (size_t)li * C_;
    const float* g1n = (li < NL_-1) ? ln1g + (size_t)(li+1) * C_ : nullptr;
    const float* b1n = (li < NL_-1) ? ln1b + (size_t)(li+1) * C_ : nullptr;

    // QKV = y @ [Wq;Wk;Wv]^T + b  (B-panel LDS-staged)
    sgemm_kernel<0><<<gqkv, blk, 0, stream>>>(yb, wqkv_b, bqkv_l, nullptr,
        qkvb, nullptr, nullptr, nullptr, 384);

    // attention + head scramble -> sb
    attn_kernel<<<B_*L_, blk, 0, stream>>>(qkvb, sb);

    // z = LN_A(y + sb@Wo^T + bo): yf/yb in place  (Wo panel LDS-staged)
    sgemm_kernel<1><<<g64, blk, 0, stream>>>(sb, wo_b, bo_l, yf,
        yb, yf, gA, bA, 128);

    // FF block #1 (fused): u3 = LN_F(z + f(z)) -> yf/yb
    ffuse_kernel<0><<<g64, blk, 0, stream>>>(yb, yf, w1_b, w2_b,
        b1_l, b2_l, gF, bF, nullptr, nullptr, yb, yf, nullptr);

    // FF block #2 (fused): h = LN_F(u3 + f(u3)); y_next = LN1(h) (or h->out at end)
    ffuse_kernel<1><<<g64, blk, 0, stream>>>(yb, yf, w1_b, w2_b,
        b1_l, b2_l, gF, bF, g1n, b1n, yb, yf,
        (li == NL_-1) ? out : nullptr);
  }
  (void)in_sizes; (void)n_in; (void)out_size; (void)ws_size;
}

// Round 23
// 675.850 us; speedup vs baseline: 1.2469x; 1.2469x over previous
//
#include <hip/hip_runtime.h>
#include <math.h>

#define B_ 8
#define L_ 256
#define N_ 22
#define C_ 128
#define H_ 8
#define DK_ 16
#define DFF_ 512
#define NL_ 6
#define MTOK (B_*L_*N_)   // 45056

typedef __bf16 bf16x8 __attribute__((ext_vector_type(8)));
typedef float  f32x4  __attribute__((ext_vector_type(4)));

__device__ __forceinline__ float wave_sum(float v){
#pragma unroll
  for (int i = 32; i >= 1; i >>= 1) v += __shfl_xor(v, i, 64);
  return v;
}

// fast mish: x * tanh(softplus(x)) == x*num/(num+2), num=t(t+2), t=e^x.
// den = num+2 >= 2 -> v_rcp_f32 (~1ulp) safe; error far below bf16 rounding.
__device__ __forceinline__ float mishf(float x){
  float t = __expf(fminf(x, 20.0f));
  float num = t * (t + 2.0f);
  return x * num * __builtin_amdgcn_rcpf(num + 2.0f);
}

// ---------------- fused entry: o = x + LN(x+pe; peg,peb); y = LN(o; g1,b1) ------
__global__ __launch_bounds__(256) void pe_ln_kernel(
    const float* __restrict__ x, const float* __restrict__ g,
    const float* __restrict__ b, const float* __restrict__ g1,
    const float* __restrict__ b1, float* __restrict__ yf,
    __bf16* __restrict__ yb)
{
  int row  = (blockIdx.x * 256 + threadIdx.x) >> 6;   // token index
  int lane = threadIdx.x & 63;
  if (row >= MTOK) return;
  int bl = row / N_;            // b*L + l
  int l  = bl & (L_ - 1);
  const float* xr = x + (size_t)row * C_;
  float x0 = xr[lane], x1 = xr[lane + 64];
  int c0 = lane, c1 = lane + 64;
  const float LOG1E4 = 9.210340371976184f;
  float e0 = __expf(LOG1E4 * (-2.0f * (float)c0 / 128.0f));
  float e1 = __expf(LOG1E4 * (-2.0f * (float)c1 / 128.0f));
  float a0 = (float)l * e0, a1 = (float)l * e1;
  float pe0 = (c0 & 1) ? cosf(a0) : sinf(a0);
  float pe1 = (c1 & 1) ? cosf(a1) : sinf(a1);
  float t0 = x0 + pe0, t1 = x1 + pe1;
  float mean = wave_sum(t0 + t1) * (1.0f/128.0f);
  float d0 = t0 - mean, d1 = t1 - mean;
  float var = wave_sum(d0*d0 + d1*d1) * (1.0f/128.0f);
  float inv = rsqrtf(var + 1e-5f);
  float o0 = x0 + d0 * inv * g[c0] + b[c0];
  float o1 = x1 + d1 * inv * g[c1] + b[c1];
  float m2 = wave_sum(o0 + o1) * (1.0f/128.0f);
  float e0d = o0 - m2, e1d = o1 - m2;
  float v2 = wave_sum(e0d*e0d + e1d*e1d) * (1.0f/128.0f);
  float i2 = rsqrtf(v2 + 1e-5f);
  float y0 = e0d * i2 * g1[c0] + b1[c0];
  float y1 = e1d * i2 * g1[c1] + b1[c1];
  float* yrow = yf + (size_t)row * C_;
  yrow[c0] = y0;
  yrow[c1] = y1;
  __bf16* brow = yb + (size_t)row * C_;
  brow[c0] = (__bf16)y0;
  brow[c1] = (__bf16)y1;
}

// ---------------- weight pack fp32 -> bf16 arena, FRAGMENT-MAJOR ----------------
// frag (nb,kb): rows nb*16..+15 x k kb*32..+31 as 512 contiguous elems:
// element (n = nb*16 + (lane&15), k = kb*32 + (lane>>4)*8 + j) at
// off = ((nb*KB + kb)*64 + lane)*8 + j  -> 1KB coalesced wave burst per frag.
// QKV [0,589824) per-layer 49152 (nb<24,KB=4); Wo [..688128) (nb<8,KB=4);
// W1 [..1081344) (nb<32,KB=4); W2 [..1474560) (nb<8,KB=16) with the FF1->FF2
// k-permutation composed in: src k-within-32 = (j<4 ? lh*4+j : 16+lh*4+(j-4)).
#define WQKV_END 589824
#define WO_END   688128
#define W1_END   1081344
#define WTOT     1474560
__global__ __launch_bounds__(256) void wpack_kernel(
    const float* __restrict__ Wq, const float* __restrict__ Wk,
    const float* __restrict__ Wv, const float* __restrict__ Wo,
    const float* __restrict__ W1, const float* __restrict__ W2,
    __bf16* __restrict__ dst)
{
  int i = blockIdx.x * 256 + threadIdx.x;
  float v;
  if (i < WQKV_END) {
    int li = i / 49152, rem = i % 49152;
    int j = rem & 7, lane = (rem >> 3) & 63, fr = rem >> 9;
    int kb = fr & 3, nb = fr >> 2;
    int n = nb*16 + (lane & 15);
    int k = kb*32 + (lane >> 4)*8 + j;
    int which = n >> 7, nr = n & 127;
    const float* W = which == 0 ? Wq : which == 1 ? Wk : Wv;
    v = W[li*16384 + nr*128 + k];
  } else if (i < WO_END) {
    int rel = i - WQKV_END;
    int li = rel / 16384, rem = rel % 16384;
    int j = rem & 7, lane = (rem >> 3) & 63, fr = rem >> 9;
    int kb = fr & 3, nb = fr >> 2;
    int n = nb*16 + (lane & 15), k = kb*32 + (lane >> 4)*8 + j;
    v = Wo[li*16384 + n*128 + k];
  } else if (i < W1_END) {
    int rel = i - WO_END;
    int li = rel / 65536, rem = rel % 65536;
    int j = rem & 7, lane = (rem >> 3) & 63, fr = rem >> 9;
    int kb = fr & 3, nb = fr >> 2;
    int n = nb*16 + (lane & 15), k = kb*32 + (lane >> 4)*8 + j;
    v = W1[li*65536 + n*128 + k];
  } else {
    int rel = i - W1_END;
    int li = rel / 65536, rem = rel % 65536;
    int j = rem & 7, lane = (rem >> 3) & 63, fr = rem >> 9;
    int kb = fr & 15, nb = fr >> 4;
    int n = nb*16 + (lane & 15);
    int lh = lane >> 4;
    int base = kb*32;
    int srck = base + (j < 4 ? lh*4 + j : 16 + lh*4 + (j - 4));
    v = W2[li*65536 + n*512 + srck];
  }
  dst[i] = (__bf16)v;
}

// pack QKV biases: [NL][384] fp32
__global__ __launch_bounds__(256) void bpack_kernel(
    const float* __restrict__ bq, const float* __restrict__ bk,
    const float* __restrict__ bv, float* __restrict__ dst)
{
  int i = blockIdx.x * 256 + threadIdx.x;   // < NL*384
  int li = i / 384, p = i % 384;
  float v = p < 128 ? bq[li*128 + p] : p < 256 ? bk[li*128 + p - 128] : bv[li*128 + p - 256];
  dst[i] = v;
}

// ---------------- LDS-staged gemm: B-panel (32KB, contiguous frags) in LDS ------
// Block = 64 tokens, 4 waves; panel = frags [blockIdx.y*32, +32) staged linearly.
// LN=0: outb = bf16(acc+bias). LN=1 (Ntot==128): v=acc+bias+res; y=LN(v)->outf+outb.
template<int LN>
__global__ __launch_bounds__(256, 4) void sgemm_kernel(
    const __bf16* __restrict__ A, const __bf16* __restrict__ Bw,
    const float* __restrict__ bias, const float* __restrict__ res,
    __bf16* __restrict__ outb, float* __restrict__ outf,
    const float* __restrict__ g1, const float* __restrict__ b1v,
    int Ntot)
{
  __shared__ __align__(16) char sW[32768];
  const int tid  = threadIdx.x;
  const int lane = tid & 63;
  const int wv   = tid >> 6;
  const int l15  = lane & 15;
  const int lh   = lane >> 4;
  const int tok0 = (blockIdx.x * 4 + wv) * 16;
  const int bn   = blockIdx.y * 128;

  // stage panel: contiguous 32KB at arena byte offset blockIdx.y*32768
  const char* wsrc = (const char*)Bw + (size_t)blockIdx.y * 32768;
#pragma unroll
  for (int i = 0; i < 8; ++i) {
    int id = i*256 + tid;
    __builtin_amdgcn_global_load_lds((const unsigned int*)(wsrc + (size_t)id*16),
        (unsigned int*)(sW + (size_t)(i*256 + wv*64)*16), 16, 0, 0);
  }

  bf16x8 az[4];
#pragma unroll
  for (int ks = 0; ks < 4; ++ks)
    az[ks] = *(const bf16x8*)(A + (size_t)(tok0 + l15) * 128 + ks*32 + lh*8);

  __syncthreads();   // staging visible (compiler drains vmcnt before barrier)

  f32x4 acc[8] = {};
#pragma unroll
  for (int ks = 0; ks < 4; ++ks)
#pragma unroll
    for (int fc = 0; fc < 8; ++fc) {
      bf16x8 bw = *(const bf16x8*)(sW + (size_t)(fc*4 + ks)*1024 + lane*16);
      acc[fc] = __builtin_amdgcn_mfma_f32_16x16x32_bf16(az[ks], bw, acc[fc], 0, 0, 0);
    }

  if (LN == 0) {
#pragma unroll
    for (int fc = 0; fc < 8; ++fc) {
      int col = bn + fc*16 + l15;
      float bc = bias[col];
#pragma unroll
      for (int r = 0; r < 4; ++r)
        outb[(size_t)(tok0 + lh*4 + r) * Ntot + col] = (__bf16)(acc[fc][r] + bc);
    }
  } else {
#pragma unroll
    for (int fc = 0; fc < 8; ++fc) {
      int col = fc*16 + l15;
      float bc = bias[col];
#pragma unroll
      for (int r = 0; r < 4; ++r)
        acc[fc][r] += bc + res[(size_t)(tok0 + lh*4 + r) * 128 + col];
    }
    float mean[4], inv[4];
#pragma unroll
    for (int r = 0; r < 4; ++r) {
      float s = 0.0f, q = 0.0f;
#pragma unroll
      for (int fc = 0; fc < 8; ++fc) { s += acc[fc][r]; q += acc[fc][r]*acc[fc][r]; }
#pragma unroll
      for (int msk = 1; msk <= 8; msk <<= 1) {
        s += __shfl_xor(s, msk, 64);
        q += __shfl_xor(q, msk, 64);
      }
      float m = s * (1.0f/128.0f);
      mean[r] = m;
      inv[r]  = rsqrtf(q * (1.0f/128.0f) - m*m + 1e-5f);
    }
#pragma unroll
    for (int fc = 0; fc < 8; ++fc) {
      int col = fc*16 + l15;
      float gc = g1[col], bc = b1v[col];
#pragma unroll
      for (int r = 0; r < 4; ++r) {
        float y = (acc[fc][r] - mean[r]) * inv[r] * gc + bc;
        size_t idx = (size_t)(tok0 + lh*4 + r) * 128 + col;
        outf[idx] = y;
        outb[idx] = (__bf16)y;
      }
    }
  }
}

// ---------------- fused FF residual block v10: pipelined 16KB-chunk dbuf --------
// Block = 64 tokens, 4 waves (wave = 16 tokens, ALL 128 output cols).
// 16 chunks of 32 dff; double-buffered in 2x16KB (32KB). Issue next chunk's
// global_load_lds before computing current. LN epilogue wave-local.
template<int SECOND>
__global__ __launch_bounds__(256, 4) void ffuse_kernel(
    const __bf16* __restrict__ zb, const float* __restrict__ resf,
    const __bf16* __restrict__ W1g, const __bf16* __restrict__ W2g,
    const float* __restrict__ b1, const float* __restrict__ b2,
    const float* __restrict__ g1, const float* __restrict__ b1v,
    const float* __restrict__ g2, const float* __restrict__ b2v,
    __bf16* __restrict__ outb, float* __restrict__ outf,
    float* __restrict__ hout)
{
  __shared__ __align__(16) char smem[32768];   // 2 x (8KB sW1 + 8KB sW2)

  const int tid  = threadIdx.x;
  const int lane = tid & 63;
  const int wv   = tid >> 6;
  const int l15  = lane & 15;
  const int lh   = lane >> 4;
  const int tok0 = blockIdx.x * 64 + wv * 16;

  // z B-frags (token tok0+l15, k = ks*32 + lh*8) -- proven global path
  bf16x8 bz[4];
#pragma unroll
  for (int ks = 0; ks < 4; ++ks)
    bz[ks] = *(const bf16x8*)(zb + (size_t)(tok0 + l15) * 128 + ks*32 + lh*8);

  f32x4 accC[8] = {};

  // STAGE(chunk c -> buffer bb): W1c 8KB contiguous; W2c 8 frags (kb == c).
#define STAGE_W(c, bb) do { \
    char* sW1d = smem + (bb)*16384; \
    char* sW2d = sW1d + 8192; \
    _Pragma("unroll") \
    for (int i = 0; i < 2; ++i) { \
      int id = i*256 + tid; \
      const char* gsrc = (const char*)W1g + (size_t)(c)*8192 + (size_t)id*16; \
      __builtin_amdgcn_global_load_lds((const unsigned int*)gsrc, \
          (unsigned int*)(sW1d + (size_t)(i*256 + wv*64)*16), 16, 0, 0); \
    } \
    _Pragma("unroll") \
    for (int i = 0; i < 2; ++i) { \
      int f = i*4 + wv; \
      const char* gsrc = (const char*)W2g + ((size_t)(f*16 + (c))*64 + lane)*16; \
      __builtin_amdgcn_global_load_lds((const unsigned int*)gsrc, \
          (unsigned int*)(sW2d + (size_t)f * 1024), 16, 0, 0); \
    } \
  } while (0)

  STAGE_W(0, 0);
  __syncthreads();                 // chunk 0 staged

  int cur = 0;
  for (int ch = 0; ch < 16; ++ch) {
    if (ch < 15) STAGE_W(ch + 1, cur ^ 1);   // issue next chunk's loads first

    const char* sW1 = smem + cur*16384;
    const char* sW2 = sW1 + 8192;

    // ---- FF1 (swapped): accM[fn] over this 32-dff chunk ----
    f32x4 accM[2] = {};
#pragma unroll
    for (int ks = 0; ks < 4; ++ks)
#pragma unroll
      for (int fn = 0; fn < 2; ++fn) {
        bf16x8 aw = *(const bf16x8*)(sW1 + (size_t)(fn*4 + ks)*1024 + lane*16);
        accM[fn] = __builtin_amdgcn_mfma_f32_16x16x32_bf16(aw, bz[ks], accM[fn], 0, 0, 0);
      }
    // bias + mish
#pragma unroll
    for (int fn = 0; fn < 2; ++fn) {
      f32x4 bb = *(const f32x4*)(b1 + ch*32 + fn*16 + lh*4);
#pragma unroll
      for (int r = 0; r < 4; ++r)
        accM[fn][r] = mishf(accM[fn][r] + bb[r]);
    }
    // ---- FF2: one A-frag from accM pair (W2 k-permutation composed at pack) ----
    {
      bf16x8 am;
#pragma unroll
      for (int j = 0; j < 4; ++j) {
        am[j]     = (__bf16)accM[0][j];
        am[j + 4] = (__bf16)accM[1][j];
      }
#pragma unroll
      for (int fc = 0; fc < 8; ++fc) {
        bf16x8 bw = *(const bf16x8*)(sW2 + (size_t)fc*1024 + lane*16);
        accC[fc] = __builtin_amdgcn_mfma_f32_16x16x32_bf16(am, bw, accC[fc], 0, 0, 0);
      }
    }
    __syncthreads();   // prefetch drained (after compute) + buffer-reuse fence
    cur ^= 1;
  }
#undef STAGE_W

  // ---- epilogue: bias + residual, wave-local LN (proven sgemm<1> shape) ----
#pragma unroll
  for (int fc = 0; fc < 8; ++fc) {
    int col = fc*16 + l15;
    float bc = b2[col];
#pragma unroll
    for (int r = 0; r < 4; ++r)
      accC[fc][r] += bc + resf[(size_t)(tok0 + lh*4 + r) * 128 + col];
  }
  float mean[4], inv[4];
#pragma unroll
  for (int r = 0; r < 4; ++r) {
    float s = 0.0f, q = 0.0f;
#pragma unroll
    for (int fc = 0; fc < 8; ++fc) { s += accC[fc][r]; q += accC[fc][r]*accC[fc][r]; }
#pragma unroll
    for (int msk = 1; msk <= 8; msk <<= 1) {
      s += __shfl_xor(s, msk, 64);
      q += __shfl_xor(q, msk, 64);
    }
    float m = s * (1.0f/128.0f);
    mean[r] = m;
    inv[r]  = rsqrtf(q * (1.0f/128.0f) - m*m + 1e-5f);
  }

  if (SECOND == 0) {
#pragma unroll
    for (int fc = 0; fc < 8; ++fc) {
      int col = fc*16 + l15;
      float gc = g1[col], bc = b1v[col];
#pragma unroll
      for (int r = 0; r < 4; ++r) {
        float y = (accC[fc][r] - mean[r]) * inv[r] * gc + bc;
        size_t idx = (size_t)(tok0 + lh*4 + r) * 128 + col;
        outf[idx] = y;
        outb[idx] = (__bf16)y;
      }
    }
  } else {
    // h = LN_F(v)
#pragma unroll
    for (int fc = 0; fc < 8; ++fc) {
      int col = fc*16 + l15;
      float gc = g1[col], bc = b1v[col];
#pragma unroll
      for (int r = 0; r < 4; ++r) {
        float h = (accC[fc][r] - mean[r]) * inv[r] * gc + bc;
        accC[fc][r] = h;
        if (hout) hout[(size_t)(tok0 + lh*4 + r) * 128 + col] = h;
      }
    }
    if (g2 != nullptr) {
#pragma unroll
      for (int r = 0; r < 4; ++r) {
        float s = 0.0f, q = 0.0f;
#pragma unroll
        for (int fc = 0; fc < 8; ++fc) { s += accC[fc][r]; q += accC[fc][r]*accC[fc][r]; }
#pragma unroll
        for (int msk = 1; msk <= 8; msk <<= 1) {
          s += __shfl_xor(s, msk, 64);
          q += __shfl_xor(q, msk, 64);
        }
        float m = s * (1.0f/128.0f);
        mean[r] = m;
        inv[r]  = rsqrtf(q * (1.0f/128.0f) - m*m + 1e-5f);
      }
#pragma unroll
      for (int fc = 0; fc < 8; ++fc) {
        int col = fc*16 + l15;
        float gc = g2[col], bc = b2v[col];
#pragma unroll
        for (int r = 0; r < 4; ++r) {
          float y = (accC[fc][r] - mean[r]) * inv[r] * gc + bc;
          size_t idx = (size_t)(tok0 + lh*4 + r) * 128 + col;
          outf[idx] = y;
          outb[idx] = (__bf16)y;
        }
      }
    }
  }
}

// ---------------- attention over nodes, block per (b,l), scatter-scrambled out ---
__global__ __launch_bounds__(256) void attn_kernel(
    const __bf16* __restrict__ qkv, __bf16* __restrict__ out)
{
  __shared__ float Ks[N_ * C_];
  __shared__ float Vs[N_ * C_];
  int bl = blockIdx.x;            // b*L + l
  int b  = bl >> 8;
  int l  = bl & (L_ - 1);
  size_t mb = (size_t)bl * N_;
  for (int i = threadIdx.x; i < N_ * C_; i += 256) {
    int row = i >> 7, c = i & 127;
    Ks[i] = (float)qkv[(mb + row) * 384 + 128 + c];
    Vs[i] = (float)qkv[(mb + row) * 384 + 256 + c];
  }
  __syncthreads();
  int h  = threadIdx.x >> 5;
  int nq = threadIdx.x & 31;
  if (nq >= N_) return;
  float qr[DK_];
  const __bf16* qp = qkv + (mb + nq) * 384 + h * DK_;
#pragma unroll
  for (int d = 0; d < DK_; ++d) qr[d] = (float)qp[d];
  float sc[N_];
#pragma unroll
  for (int m = 0; m < N_; ++m) {
    float s = 0.0f;
#pragma unroll
    for (int d = 0; d < DK_; ++d) s = fmaf(qr[d], Ks[m*C_ + h*DK_ + d], s);
    sc[m] = s * 0.25f;
  }
  float mx = -1e30f;
#pragma unroll
  for (int m = 0; m < N_; ++m) mx = fmaxf(mx, sc[m]);
  float sum = 0.0f;
#pragma unroll
  for (int m = 0; m < N_; ++m) { sc[m] = __expf(sc[m] - mx); sum += sc[m]; }
  float rs = __builtin_amdgcn_rcpf(sum);
  float o[DK_];
#pragma unroll
  for (int d = 0; d < DK_; ++d) o[d] = 0.0f;
#pragma unroll
  for (int m = 0; m < N_; ++m)
#pragma unroll
    for (int d = 0; d < DK_; ++d) o[d] = fmaf(sc[m], Vs[m*C_ + h*DK_ + d], o[d]);
  int flat = nq * L_ + l;
  int l2 = flat / N_;
  int n2 = flat - l2 * N_;
  __bf16* op = out + ((size_t)((b * L_ + l2) * N_ + n2)) * C_ + h * DK_;
#pragma unroll
  for (int d = 0; d < DK_; ++d) op[d] = (__bf16)(o[d] * rs);
}

extern "C" void kernel_launch(void* const* d_in, const int* in_sizes, int n_in,
                              void* d_out, int out_size, void* d_ws, size_t ws_size,
                              hipStream_t stream) {
  const float* x    = (const float*)d_in[0];
  const float* Wq   = (const float*)d_in[1];
  const float* bq   = (const float*)d_in[2];
  const float* Wk   = (const float*)d_in[3];
  const float* bk   = (const float*)d_in[4];
  const float* Wv   = (const float*)d_in[5];
  const float* bv   = (const float*)d_in[6];
  const float* Wo   = (const float*)d_in[7];
  const float* bo   = (const float*)d_in[8];
  const float* W1   = (const float*)d_in[9];
  const float* bf1  = (const float*)d_in[10];
  const float* W2   = (const float*)d_in[11];
  const float* bf2  = (const float*)d_in[12];
  const float* ln1g = (const float*)d_in[13];
  const float* ln1b = (const float*)d_in[14];
  const float* lnAg = (const float*)d_in[15];
  const float* lnAb = (const float*)d_in[16];
  const float* lnFg = (const float*)d_in[17];
  const float* lnFb = (const float*)d_in[18];
  const float* peg  = (const float*)d_in[19];
  const float* peb  = (const float*)d_in[20];

  float* out = (float*)d_out;
  char*  ws  = (char*)d_ws;
  const size_t U = (size_t)MTOK * C_;

  __bf16* wbf   = (__bf16*)ws;                         // 2,949,120 B weight arena
  float*  bqkv  = (float*)(ws + 2949120);              // NL*384*4
  float*  yf    = (float*)(ws + 2958592);              // U*4 fp32 residual/LN base
  __bf16* yb    = (__bf16*)(ws + 2958592 + U*4);       // U*2 bf16 LN out
  __bf16* qkvb  = (__bf16*)(ws + 2958592 + U*6);       // 3U*2 packed QKV
  __bf16* sb    = (__bf16*)(ws + 2958592 + U*12);      // U*2 scrambled attn out

  dim3 blk(256);
  const int lnGrid = MTOK / 4;
  dim3 gqkv(MTOK/64, 3);
  dim3 g64(MTOK/64, 1);

  wpack_kernel<<<WTOT/256, blk, 0, stream>>>(Wq, Wk, Wv, Wo, W1, W2, wbf);
  bpack_kernel<<<NL_*384/256, blk, 0, stream>>>(bq, bk, bv, bqkv);
  pe_ln_kernel<<<lnGrid, blk, 0, stream>>>(x, peg, peb, ln1g, ln1b, yf, yb);

  for (int li = 0; li < NL_; ++li) {
    const __bf16* wqkv_b = wbf + (size_t)li * 49152;
    const __bf16* wo_b   = wbf + WQKV_END + (size_t)li * 16384;
    const __bf16* w1_b   = wbf + WO_END   + (size_t)li * 65536;
    const __bf16* w2_b   = wbf + W1_END   + (size_t)li * 65536;
    const float* bqkv_l = bqkv + (size_t)li * 384;
    const float* bo_l = bo + (size_t)li * 128;
    const float* b1_l = bf1 + (size_t)li * 512;
    const float* b2_l = bf2 + (size_t)li * 128;
    const float* gA = lnAg + (size_t)li * C_; const float* bA = lnAb + (size_t)li * C_;
    const float* gF = lnFg + (size_t)li * C_; const float* bF = lnFb + (size_t)li * C_;
    const float* g1n = (li < NL_-1) ? ln1g + (size_t)(li+1) * C_ : nullptr;
    const float* b1n = (li < NL_-1) ? ln1b + (size_t)(li+1) * C_ : nullptr;

    // QKV = y @ [Wq;Wk;Wv]^T + b  (B-panel LDS-staged)
    sgemm_kernel<0><<<gqkv, blk, 0, stream>>>(yb, wqkv_b, bqkv_l, nullptr,
        qkvb, nullptr, nullptr, nullptr, 384);

    // attention + head scramble -> sb
    attn_kernel<<<B_*L_, blk, 0, stream>>>(qkvb, sb);

    // z = LN_A(y + sb@Wo^T + bo): yf/yb in place  (Wo panel LDS-staged)
    sgemm_kernel<1><<<g64, blk, 0, stream>>>(sb, wo_b, bo_l, yf,
        yb, yf, gA, bA, 128);

    // FF block #1 (fused): u3 = LN_F(z + f(z)) -> yf/yb
    ffuse_kernel<0><<<g64, blk, 0, stream>>>(yb, yf, w1_b, w2_b,
        b1_l, b2_l, gF, bF, nullptr, nullptr, yb, yf, nullptr);

    // FF block #2 (fused): h = LN_F(u3 + f(u3)); y_next = LN1(h) (or h->out at end)
    ffuse_kernel<1><<<g64, blk, 0, stream>>>(yb, yf, w1_b, w2_b,
        b1_l, b2_l, gF, bF, g1n, b1n, yb, yf,
        (li == NL_-1) ? out : nullptr);
  }
  (void)in_sizes; (void)n_in; (void)out_size; (void)ws_size;
}